// Round 17
// baseline (26.761 us; speedup 1.0000x reference)
//
#include <hip/hip_runtime.h>
#include <math.h>

#define N  2048
#define K  8
#define NK 1024
#define R  4             // rows per block
#define TPB 512
#define SLOT NK          // zero slot index in stage rows
#define TAU_C 0.5f
#define TAU_S 0.5f

// HBM -> LDS direct DMA, 16B per lane. LDS dest = uniform base + lane*16 (HW
// rule), so dest must be linear in lane order -- ours is (contiguous row
// chunk). No destination VGPRs -> the register allocator cannot re-fuse the
// load into its consumer (the failure mode of R4/R6/R10 reg staging).
__device__ __forceinline__ void async_copy16(const float* g, float* l) {
    __builtin_amdgcn_global_load_lds(
        (__attribute__((address_space(1))) void*)(uintptr_t)(g),
        (__attribute__((address_space(3))) void*)(uint32_t)(uintptr_t)(l),
        16, 0, 0);
}

// Single fused kernel (replay-safe class, R8-R16). R16 structure (22.3us) with
// the staging round-trip replaced by double-buffered global_load_lds DMA:
// row r+1's stage flies during row r's compute; ONE vmcnt(0)+barrier per row.
__global__ void __launch_bounds__(TPB, 4)
fia_fused(const float* __restrict__ adj,
          const int*   __restrict__ idx,
          float* __restrict__ out) {
    __shared__ union {
        short jj[K][N];                 // 32 KB, dead after jc hoist
        float st[2][K][NK + 4];         // 64.3 KB double-buffered stage
    } u;                                // st[0] aliases jj
    __shared__ short  ixs[K][R];        // pos of row x in idx[k], or -1
    __shared__ float  lutCS[81];        // exact IEEE cs/n (ref C bits)
    __shared__ float2 lutB[81];         // (BloN, BhiN) decision bounds on vs

    const int tid  = threadIdx.x;
    const int lane = tid & 63;
    const int wid  = tid >> 6;          // wave id, 0..7
    const int X0   = blockIdx.x * R;

    // ---- one-time init: jj=-1, ixs=-1, decision LUTs (R16-proven)
    {
        int4  m1 = make_int4(-1, -1, -1, -1);
        int4* p4 = (int4*)&u.jj[0][0];               // 2048 int4
        #pragma unroll
        for (int q = 0; q < (K * N * 2) / (16 * TPB); ++q)   // 4
            p4[q * TPB + tid] = m1;
        if (tid < K * R) ((short*)ixs)[tid] = (short)-1;
        if (tid < 81) {
            int cn = tid / 9, cc = tid % 9;
            float nn = fmaxf((float)cn, 1e-5f);
            float C  = (float)cc / nn;               // IEEE divide == ref C bits
            lutCS[tid] = C;
            float lo, hi;
            if (2 * cc <= cn) { lo = -2.0f; hi = -1.0f; }    // always reject
            else {
                float B = logf(2.0f * C);            // V boundary: S = 0.5
                float d = 1e-3f * (1.0f + fabsf(B)); // >=1000x all err sources
                lo = (B - d) * (float)cn;
                hi = (B + d) * (float)cn;
            }
            lutB[tid] = make_float2(lo, hi);
        }
    }
    __syncthreads();

    // ---- scan idx: int4 loads (R16-proven). Unique writer per cell.
    #pragma unroll
    for (int it = 0; it < (K * NK) / (4 * TPB); ++it) {      // 4
        int  t4   = it * TPB + tid;
        int4 w    = ((const int4*)idx)[t4];          // coalesced 16B
        int  base = t4 * 4;
        int  k    = base >> 10;
        int  p    = base & (NK - 1);
        u.jj[k][w.x] = (short)(p);
        u.jj[k][w.y] = (short)(p + 1);
        u.jj[k][w.z] = (short)(p + 2);
        u.jj[k][w.w] = (short)(p + 3);
        int r0 = w.x - X0, r1 = w.y - X0, r2 = w.z - X0, r3 = w.w - X0;
        if ((unsigned)r0 < (unsigned)R) ixs[k][r0] = (short)(p);
        if ((unsigned)r1 < (unsigned)R) ixs[k][r1] = (short)(p + 1);
        if ((unsigned)r2 < (unsigned)R) ixs[k][r2] = (short)(p + 2);
        if ((unsigned)r3 < (unsigned)R) ixs[k][r3] = (short)(p + 3);
    }
    __syncthreads();

    // ---- hoist per-thread column state from jj (last use of jj)
    const int y0 = tid * 4;                          // 4 consecutive columns
    int jc[K][4];                                    // gather index or SLOT
    int jmask[4] = {0, 0, 0, 0};
    #pragma unroll
    for (int k = 0; k < K; ++k) {
        short4 v = *(const short4*)&u.jj[k][y0];     // ds_read_b64
        int j0 = v.x, j1 = v.y, j2 = v.z, j3 = v.w;
        jmask[0] |= (j0 >= 0) ? (1 << k) : 0;
        jmask[1] |= (j1 >= 0) ? (1 << k) : 0;
        jmask[2] |= (j2 >= 0) ? (1 << k) : 0;
        jmask[3] |= (j3 >= 0) ? (1 << k) : 0;
        jc[k][0] = (j0 >= 0) ? j0 : SLOT;            // absent -> zero slot
        jc[k][1] = (j1 >= 0) ? j1 : SLOT;
        jc[k][2] = (j2 >= 0) ? j2 : SLOT;
        jc[k][3] = (j3 >= 0) ? j3 : SLOT;
    }
    __syncthreads();                                 // jj dead; st[0] writable

    // ---- zero slots for both buffers (DMA never touches [SLOT])
    if (tid < K)          u.st[0][tid][SLOT] = 0.0f;
    else if (tid < 2 * K) u.st[1][tid - K][SLOT] = 0.0f;

    // ---- prologue: issue row-0 DMA into st[0]
    {
        int kp0 = 0, ix0[K];
        #pragma unroll
        for (int k = 0; k < K; ++k) {
            int v = (int)ixs[k][0];
            ix0[k] = __builtin_amdgcn_readfirstlane(v);
            kp0 |= (ix0[k] >= 0) ? (1 << k) : 0;
        }
        int slot = 0;
        #pragma unroll
        for (int k = 0; k < K; ++k) {
            if ((kp0 >> k) & 1) {                    // wave-uniform branch
                const float* rowg = adj + ((size_t)k * NK + (size_t)ix0[k]) * NK;
                #pragma unroll
                for (int q = 0; q < 4; ++q) {        // 4 x 1KB chunks
                    if ((slot & 7) == wid)
                        async_copy16(rowg + q * 256 + lane * 4,
                                     &u.st[0][k][q * 256]);
                    ++slot;
                }
            }
        }
    }
    asm volatile("s_waitcnt vmcnt(0)" ::: "memory");
    __syncthreads();                                 // st[0] ready (+zero slots)

    // ---- row loop: compute row r from st[r&1] while DMA fills st[(r+1)&1]
    #pragma unroll 1
    for (int r = 0; r < R; ++r) {
        const int cur = r & 1;

        // current row's presence (cheap LDS re-read, avoids cross-iter carry)
        int kpC = 0;
        {
            #pragma unroll
            for (int k = 0; k < K; ++k) {
                int v = (int)ixs[k][r];
                kpC |= (__builtin_amdgcn_readfirstlane(v) >= 0) ? (1 << k) : 0;
            }
        }

        // issue next row's DMA into the other buffer (safe: all waves done
        // reading it, guaranteed by the previous end-of-row barrier)
        if (r + 1 < R) {
            const int nxt = cur ^ 1;
            int kpN = 0, ixN[K];
            #pragma unroll
            for (int k = 0; k < K; ++k) {
                int v = (int)ixs[k][r + 1];
                ixN[k] = __builtin_amdgcn_readfirstlane(v);
                kpN |= (ixN[k] >= 0) ? (1 << k) : 0;
            }
            int slot = 0;
            #pragma unroll
            for (int k = 0; k < K; ++k) {
                if ((kpN >> k) & 1) {
                    const float* rowg = adj + ((size_t)k * NK + (size_t)ixN[k]) * NK;
                    #pragma unroll
                    for (int q = 0; q < 4; ++q) {
                        if ((slot & 7) == wid)
                            async_copy16(rowg + q * 256 + lane * 4,
                                         &u.st[nxt][k][q * 256]);
                        ++slot;
                    }
                }
            }
        }

        // PASS A: gather + sum + cs from st[cur] (select-free via zero slot)
        float vraw[4][K];
        float sum[4] = {0.f, 0.f, 0.f, 0.f};
        int   csi[4] = {0, 0, 0, 0};
        #pragma unroll
        for (int k = 0; k < K; ++k) {
            if ((kpC >> k) & 1) {                    // SGPR branch
                #pragma unroll
                for (int yy = 0; yy < 4; ++yy) {
                    float a = u.st[cur][k][jc[k][yy]];   // ds_read_b32
                    vraw[yy][k] = a;
                    sum[yy] += a;                    // +0.0 for absent == ref
                    csi[yy] += (a > TAU_C) ? 1 : 0;  // absent a=0 -> false
                }
            }
        }

        // PASS B + epilogue: mean (exact), vs (exact), bounds decision (R16)
        float res[4];
        #pragma unroll
        for (int yy = 0; yy < 4; ++yy) {
            const int m   = jmask[yy] & kpC;
            const int cnt = __popc(m);
            float n    = fmaxf((float)cnt, 1e-5f);
            float mean = sum[yy] / n;                // IEEE divide (ref bits)

            float vs = 0.f;
            #pragma unroll
            for (int k = 0; k < K; ++k) {
                if ((kpC >> k) & 1) {                // SGPR branch
                    bool  p = (m >> k) & 1;
                    float d = vraw[yy][k] - mean;
                    vs += p ? d * d : 0.f;           // select blocks fma-fuse
                }
            }

            const int li = cnt * 9 + csi[yy];
            float2 bb = lutB[li];
            bool acc;
            if (__builtin_expect(vs >= bb.x && vs <= bb.y, 0)) {
                // in-band (~0.1%): byte-exact reference sequence
                float C = lutCS[li];
                float V = vs / n;                    // IEEE divide
                float S = C * expf(-V);              // precise expf
                acc = (S > TAU_S);
            } else {
                acc = (vs < bb.x);                   // certain accept / reject
            }
            res[yy] = acc ? mean : 0.f;              // cnt==0 -> reject -> 0
        }

        float4 o;
        o.x = res[0]; o.y = res[1]; o.z = res[2]; o.w = res[3];
        *(float4*)(out + (size_t)(X0 + r) * N + y0) = o;

        // one drain+barrier per row: next-row DMA landed; st[cur] free to reuse
        if (r + 1 < R) {
            asm volatile("s_waitcnt vmcnt(0)" ::: "memory");
            __syncthreads();
        }
    }
}

extern "C" void kernel_launch(void* const* d_in, const int* in_sizes, int n_in,
                              void* d_out, int out_size, void* d_ws, size_t ws_size,
                              hipStream_t stream) {
    const float* adj = (const float*)d_in[0];        // (K, NK, NK) f32
    const int*   idx = (const int*)d_in[1];          // (K, NK) i32
    float*       out = (float*)d_out;                // (N, N) f32

    dim3 block(TPB, 1, 1);
    dim3 grid(N / R, 1, 1);                          // 512 blocks x 4 rows
    fia_fused<<<grid, block, 0, stream>>>(adj, idx, out);
}

// Round 18
// 19.645 us; speedup vs baseline: 1.3622x; 1.3622x over previous
//
#include <hip/hip_runtime.h>
#include <math.h>

#define N  2048
#define K  8
#define NK 1024
#define R  4             // rows per block
#define TPB 512
#define SLOT NK          // zero slot index in stage rows
#define TAU_C 0.5f
#define TAU_S 0.5f

// Single fused kernel (replay-safe class, R8-R17). R16 structure (best: 22.3us,
// reg-staged LDS rows + bounds-LUT decision) with the per-output math thinned:
//  - PASS A accumulates sum, sumsq (fma), cs -- no vraw array
//  - vs via identity vs = sumsq + mean*(cnt*mean - 2*sum)  (err <~1e-5,
//    100x inside the lutB decision band, so decisions stay provably exact)
//  - mean via reciprocal LUT (bit-exact for cnt in {1,2,4,8}; <=2ulp else,
//    output tolerance 2e-2)
//  - in-band cells (~0.5%) re-gather from the live LDS stage and run the
//    byte-exact reference sequence (IEEE divides, k-ordered selects, expf)
__global__ void __launch_bounds__(TPB, 4)
fia_fused(const float* __restrict__ adj,
          const int*   __restrict__ idx,
          float* __restrict__ out) {
    __shared__ short  jj[K][N];          // 32 KB: pos of y in idx[k], or -1
    __shared__ short  ixs[K][R];         // pos of row x in idx[k], or -1
    __shared__ float  stage[K][NK + 4];  // 32.9 KB: row data + zero slot
    __shared__ float  lutCS[81];         // exact IEEE cs/n (ref C bits)
    __shared__ float2 lutB[81];          // (BloN, BhiN) decision bounds on vs
    __shared__ float  lutR[16];          // 1/max(cnt,1e-5)

    const int tid = threadIdx.x;
    const int X0  = blockIdx.x * R;

    // ---- one-time init: maps to -1, zero slots, LUTs
    {
        int4  m1 = make_int4(-1, -1, -1, -1);
        int4* p4 = (int4*)&jj[0][0];                 // 2048 int4
        #pragma unroll
        for (int q = 0; q < (K * N * 2) / (16 * TPB); ++q)   // 4
            p4[q * TPB + tid] = m1;
        if (tid < K * R) ((short*)ixs)[tid] = (short)-1;
        if (tid < K) stage[tid][SLOT] = 0.0f;        // zero slot per client
        if (tid < 16) lutR[tid] = 1.0f / fmaxf((float)tid, 1e-5f);
        if (tid < 81) {
            int cn = tid / 9, cc = tid % 9;
            float nn = fmaxf((float)cn, 1e-5f);
            float C  = (float)cc / nn;               // IEEE divide == ref C bits
            lutCS[tid] = C;
            float lo, hi;
            if (2 * cc <= cn) { lo = -2.0f; hi = -1.0f; }    // always reject
            else {
                float B = logf(2.0f * C);            // V boundary: S = 0.5
                float d = 1e-3f * (1.0f + fabsf(B)); // >=100x all err sources
                lo = (B - d) * (float)cn;
                hi = (B + d) * (float)cn;
            }
            lutB[tid] = make_float2(lo, hi);
        }
    }
    __syncthreads();

    // ---- scan idx: int4 loads (R16-proven). Unique writer per cell.
    #pragma unroll
    for (int it = 0; it < (K * NK) / (4 * TPB); ++it) {      // 4
        int  t4   = it * TPB + tid;
        int4 w    = ((const int4*)idx)[t4];          // coalesced 16B
        int  base = t4 * 4;
        int  k    = base >> 10;
        int  p    = base & (NK - 1);
        jj[k][w.x] = (short)(p);
        jj[k][w.y] = (short)(p + 1);
        jj[k][w.z] = (short)(p + 2);
        jj[k][w.w] = (short)(p + 3);
        int r0 = w.x - X0, r1 = w.y - X0, r2 = w.z - X0, r3 = w.w - X0;
        if ((unsigned)r0 < (unsigned)R) ixs[k][r0] = (short)(p);
        if ((unsigned)r1 < (unsigned)R) ixs[k][r1] = (short)(p + 1);
        if ((unsigned)r2 < (unsigned)R) ixs[k][r2] = (short)(p + 2);
        if ((unsigned)r3 < (unsigned)R) ixs[k][r3] = (short)(p + 3);
    }
    __syncthreads();

    // ---- hoisted per-thread column state (reused by all R rows)
    const int y0 = tid * 4;                          // 4 consecutive columns
    int jc[K][4];                                    // gather index or SLOT
    int jmask[4] = {0, 0, 0, 0};
    #pragma unroll
    for (int k = 0; k < K; ++k) {
        short4 v = *(const short4*)&jj[k][y0];       // ds_read_b64
        int j0 = v.x, j1 = v.y, j2 = v.z, j3 = v.w;
        jmask[0] |= (j0 >= 0) ? (1 << k) : 0;
        jmask[1] |= (j1 >= 0) ? (1 << k) : 0;
        jmask[2] |= (j2 >= 0) ? (1 << k) : 0;
        jmask[3] |= (j3 >= 0) ? (1 << k) : 0;
        jc[k][0] = (j0 >= 0) ? j0 : SLOT;            // absent -> zero slot
        jc[k][1] = (j1 >= 0) ? j1 : SLOT;
        jc[k][2] = (j2 >= 0) ? j2 : SLOT;
        jc[k][3] = (j3 >= 0) ? j3 : SLOT;
    }

    // ---- row loop (R13/R16-proven staging schedule)
    #pragma unroll 1
    for (int r = 0; r < R; ++r) {
        int kp = 0;
        int ixr[K];
        #pragma unroll
        for (int k = 0; k < K; ++k) {
            int v = (int)ixs[k][r];                  // uniform LDS read
            ixr[k] = __builtin_amdgcn_readfirstlane(v);
            kp |= (ixr[k] >= 0) ? (1 << k) : 0;
        }

        // STAGE loads first (overlap with prev row's stats in other waves)
        float2 sr[K];
        #pragma unroll
        for (int k = 0; k < K; ++k) {
            if (ixr[k] >= 0) {                       // scalar branch
                const float2* __restrict__ src =
                    (const float2*)(adj + ((size_t)k * NK + (size_t)ixr[k]) * NK);
                sr[k] = src[tid];                    // fully coalesced 8B
            }
        }
        __syncthreads();                             // WAR: prev row done w/ stage
        #pragma unroll
        for (int k = 0; k < K; ++k) {
            if (ixr[k] >= 0)
                ((float2*)&stage[k][0])[tid] = sr[k];   // ds_write_b64
        }
        __syncthreads();                             // stage visible

        // PASS A: gather + {sum, sumsq, cs}, scalar-gated; select-free.
        float sum[4]   = {0.f, 0.f, 0.f, 0.f};
        float sumsq[4] = {0.f, 0.f, 0.f, 0.f};
        int   csi[4]   = {0, 0, 0, 0};
        #pragma unroll
        for (int k = 0; k < K; ++k) {
            if ((kp >> k) & 1) {                     // SGPR branch
                #pragma unroll
                for (int yy = 0; yy < 4; ++yy) {
                    float a = stage[k][jc[k][yy]];   // ds_read_b32
                    sum[yy]   += a;                  // +0.0 for absent == ref
                    sumsq[yy]  = fmaf(a, a, sumsq[yy]);
                    csi[yy]   += (a > TAU_C) ? 1 : 0;
                }
            }
        }

        // PASS B: thin decision path; rare in-band -> byte-exact fallback.
        float res[4];
        #pragma unroll
        for (int yy = 0; yy < 4; ++yy) {
            const int m   = jmask[yy] & kp;
            const int cnt = __popc(m);
            const float cf = (float)cnt;
            float mean = sum[yy] * lutR[cnt];        // exact for cnt=1,2,4,8
            float t    = fmaf(cf, mean, -2.0f * sum[yy]);
            float vsf  = fmaf(mean, t, sumsq[yy]);   // ~vs, |err| <~1e-5

            const int li = cnt * 9 + csi[yy];
            float2 bb = lutB[li];
            float rr;
            if (__builtin_expect(vsf >= bb.x && vsf <= bb.y, 0)) {
                // in-band (~0.5%): byte-exact reference sequence, re-gather.
                float n      = fmaxf(cf, 1e-5f);
                float mean_e = sum[yy] / n;          // IEEE divide (ref bits)
                float vs = 0.f;
                #pragma unroll
                for (int k = 0; k < K; ++k) {
                    if ((kp >> k) & 1) {
                        bool  p = (m >> k) & 1;
                        float a = stage[k][jc[k][yy]];
                        float d = a - mean_e;
                        vs += p ? d * d : 0.f;       // select blocks fma-fuse
                    }
                }
                float C = lutCS[li];                 // == cs/n, same IEEE bits
                float V = vs / n;                    // IEEE divide
                float S = C * expf(-V);              // precise expf
                rr = (S > TAU_S && cnt > 0) ? mean_e : 0.f;
            } else {
                rr = (vsf < bb.x) ? mean : 0.f;      // certain accept / reject
            }
            res[yy] = rr;
        }

        float4 o;
        o.x = res[0]; o.y = res[1]; o.z = res[2]; o.w = res[3];
        *(float4*)(out + (size_t)(X0 + r) * N + y0) = o;
    }
}

extern "C" void kernel_launch(void* const* d_in, const int* in_sizes, int n_in,
                              void* d_out, int out_size, void* d_ws, size_t ws_size,
                              hipStream_t stream) {
    const float* adj = (const float*)d_in[0];        // (K, NK, NK) f32
    const int*   idx = (const int*)d_in[1];          // (K, NK) i32
    float*       out = (float*)d_out;                // (N, N) f32

    dim3 block(TPB, 1, 1);
    dim3 grid(N / R, 1, 1);                          // 512 blocks x 4 rows
    fia_fused<<<grid, block, 0, stream>>>(adj, idx, out);
}